// Round 2
// baseline (374.759 us; speedup 1.0000x reference)
//
#include <hip/hip_runtime.h>
#include <cfloat>
#include <cstdint>

#define NN 8192      // nodes
#define DD 128       // features
#define W64PR 128    // u64 bitmask words per row (8192/64)
#define TOPK 32

// monotonic float -> uint mapping (descending float == descending uint)
__device__ __forceinline__ uint32_t f2s(float f) {
  uint32_t u = __float_as_uint(f);
  return (u & 0x80000000u) ? ~u : (u | 0x80000000u);
}
__device__ __forceinline__ float s2f(uint32_t s) {
  return (s & 0x80000000u) ? __uint_as_float(s & 0x7fffffffu)
                           : __uint_as_float(~s);
}

// Bit layout (permuted, writer+reader agree):
//   int index j = 1024*c + 256*w + 4*l + comp   (c=0..7, w=wave 0..3, l=lane 0..63, comp=0..3)
//   lives at u64 word  i64 = c*16 + w*4 + comp,  bit l.
// Lookup: c=j>>10, w=(j>>8)&3, l=(j>>2)&63, comp=j&3.

// Fused prep kernel:
//   blocks [0, DD)      : exact top-32 (value,index) per feature column, descending, packed float2
//   blocks [DD, DD+NN)  : adj row -> 128-u64 bitmask (ballot transpose) + has_nbr flag
__global__ __launch_bounds__(256) void prep_kernel(
    const float* __restrict__ x, const int* __restrict__ adj,
    unsigned long long* __restrict__ bits, int* __restrict__ has_nbr,
    float2* __restrict__ tk) {
  const int b = blockIdx.x;
  const int t = threadIdx.x;
  const int lane = t & 63;
  const int wv = t >> 6;

  __shared__ unsigned long long red[4];
  __shared__ unsigned long long bcast;
  __shared__ int anyflag;

  if (b >= DD) {
    // ---- coalesced bitmask build for one adjacency row ----
    const int row = b - DD;
    const uint4* src = (const uint4*)(adj + (size_t)row * NN);
    unsigned long long* dst = bits + (size_t)row * W64PR;
    if (t == 0) anyflag = 0;
    __syncthreads();
    unsigned long long any = 0;
#pragma unroll
    for (int c = 0; c < 8; ++c) {
      uint4 v = src[c * 256 + t];   // ints [1024c+4t .. 1024c+4t+3], fully coalesced
      unsigned long long b0 = __ballot(v.x != 0);
      unsigned long long b1 = __ballot(v.y != 0);
      unsigned long long b2 = __ballot(v.z != 0);
      unsigned long long b3 = __ballot(v.w != 0);
      any |= (b0 | b1 | b2 | b3);
      if (lane == 0) {
        ulonglong2* p = (ulonglong2*)(dst + (c * 16 + wv * 4));
        ulonglong2 q0; q0.x = b0; q0.y = b1;
        ulonglong2 q1; q1.x = b2; q1.y = b3;
        p[0] = q0;
        p[1] = q1;
      }
    }
    if (lane == 0 && any) anyflag = 1;  // benign same-value race
    __syncthreads();
    if (t == 0) has_nbr[row] = anyflag;
  } else {
    // ---- exact top-32 of column x[:, d], descending; keys precomputed once ----
    const int d = b;
    unsigned long long key[32];
#pragma unroll
    for (int e = 0; e < 32; ++e) {
      int j = t * 32 + e;
      key[e] = ((unsigned long long)f2s(x[(size_t)j * DD + d]) << 32) | (unsigned)j;
    }
    unsigned long long prev = ~0ull;  // keys strictly below prev each round
    for (int k = 0; k < TOPK; ++k) {
      unsigned long long best = 0ull;
#pragma unroll
      for (int e = 0; e < 32; ++e)
        if (key[e] < prev && key[e] > best) best = key[e];
      for (int off = 32; off; off >>= 1) {
        unsigned long long o = __shfl_down(best, off, 64);
        if (o > best) best = o;
      }
      if (lane == 0) red[wv] = best;
      __syncthreads();
      if (t == 0) {
        unsigned long long m = red[0];
        for (int i = 1; i < 4; ++i) if (red[i] > m) m = red[i];
        bcast = m;
        float2 kv;
        kv.x = s2f((uint32_t)(m >> 32));
        kv.y = __int_as_float((int)(uint32_t)(m & 0xffffffffu));
        tk[k * DD + d] = kv;
      }
      __syncthreads();
      prev = bcast;
    }
  }
}

// Probe kernel: 2 rows per block; wave = 64 features of one row.
__global__ __launch_bounds__(256) void probe_kernel(
    const float* __restrict__ x, const unsigned long long* __restrict__ bits,
    const int* __restrict__ has_nbr, const float2* __restrict__ tk,
    float* __restrict__ out) {
  const int t = threadIdx.x;
  const int row = blockIdx.x * 2 + (t >> 7);
  const int d = t & 127;
  const uint32_t* rb32 = (const uint32_t*)(bits + (size_t)row * W64PR);

  float res = 0.0f;
  bool done = false;
  for (int k = 0; k < TOPK; ++k) {
    float2 kv = tk[k * DD + d];
    int idx = __float_as_int(kv.y);
    int i64 = ((idx >> 10) << 4) | (((idx >> 8) & 3) << 2) | (idx & 3);
    int l = (idx >> 2) & 63;
    uint32_t w = rb32[i64 * 2 + (l >> 5)];
    bool hit = (w >> (l & 31)) & 1u;
    if (!done && hit) { res = kv.x; done = true; }
    if (__all((int)done)) break;  // wave-uniform early exit
  }
  if (__any((int)(!done))) {
    // rare (~2^-32 per element): neighbors exist but none in top-32 -> full scan
    if (!done && has_nbr[row]) {
      float m = -FLT_MAX;
      const unsigned long long* rb64 = bits + (size_t)row * W64PR;
      for (int i = 0; i < W64PR; ++i) {
        unsigned long long bm = rb64[i];
        int base = ((i >> 4) << 10) + (((i >> 2) & 3) << 8) + (i & 3);
        while (bm) {
          int l2 = __ffsll((unsigned long long)bm) - 1;
          bm &= bm - 1;
          int j = base + 4 * l2;
          m = fmaxf(m, x[(size_t)j * DD + d]);
        }
      }
      res = m;
    }
    // !done && !has_nbr -> res stays 0 (matches reference)
  }
  out[(size_t)row * DD + d] = res;
}

extern "C" void kernel_launch(void* const* d_in, const int* in_sizes, int n_in,
                              void* d_out, int out_size, void* d_ws, size_t ws_size,
                              hipStream_t stream) {
  const float* x = (const float*)d_in[0];   // [8192,128] f32
  const int* adj = (const int*)d_in[1];     // [8192,8192] i32
  float* out = (float*)d_out;               // [8192,128] f32

  // workspace layout (~8.06 MB total)
  unsigned long long* bits = (unsigned long long*)d_ws;                 // 8 MB
  int* has_nbr = (int*)((char*)d_ws + (size_t)NN * W64PR * 8);          // 32 KB
  float2* tk = (float2*)((char*)has_nbr + (size_t)NN * 4);              // 32 KB

  prep_kernel<<<NN + DD, 256, 0, stream>>>(x, adj, bits, has_nbr, tk);
  probe_kernel<<<NN / 2, 256, 0, stream>>>(x, bits, has_nbr, tk, out);
}